// Round 1
// baseline (152679.700 us; speedup 1.0000x reference)
//
#include <hip/hip_runtime.h>
#include <math.h>

// NSE recurrent model, B=32, L=1024, K=256.
// Per step t: reader LSTM -> hr_t ; scores s_l = hr_t . mem_l ; softmax z ;
// m_rt = sum z_l mem_l ; c_t = [hr,m_rt]@cW+cb ; writer LSTM -> hw_t ;
// mem = mem*(1-z) + hw_t*z  (update fused into next step's score pass).

#define Bb 32
#define LL 1024
#define KK 256
#define N4K 1024   // 4*K
#define N2K 512    // 2*K
#define NC 8       // L-chunks per batch row in attention kernel
#define RC 128     // rows per chunk = LL/NC

__device__ __forceinline__ float sigf(float v) { return 1.0f / (1.0f + expf(-v)); }

// ---------------- init: mem <- x, zero LSTM states ----------------
__global__ void k_init(const float* __restrict__ x, float* __restrict__ mem,
                       float* __restrict__ states /* 8 * B*K floats */) {
    long long n = (long long)Bb * LL * KK;
    for (long long i = (long long)blockIdx.x * blockDim.x + threadIdx.x; i < n;
         i += (long long)gridDim.x * blockDim.x)
        mem[i] = x[i];
    for (int i = blockIdx.x * blockDim.x + threadIdx.x; i < 8 * Bb * KK;
         i += gridDim.x * blockDim.x)
        states[i] = 0.0f;
}

// ---------------- reader LSTM body (shared by two kernels) ----------------
__device__ void reader_body(int b, int tid, int t,
                            const float* __restrict__ x,
                            const float* __restrict__ rWx, const float* __restrict__ rWh,
                            const float* __restrict__ rb,
                            const float* __restrict__ hr_in, const float* __restrict__ cr_in,
                            float* __restrict__ hr_out, float* __restrict__ cr_out,
                            float* sh /* >= 512 floats */) {
    float* xs = sh;
    float* hs = sh + KK;
    xs[tid] = x[((size_t)b * LL + t) * KK + tid];
    hs[tid] = hr_in[b * KK + tid];
    __syncthreads();
    int j = tid;
    float ai = rb[j], af = rb[j + KK], ag = rb[j + 2 * KK], ao = rb[j + 3 * KK];
#pragma unroll 4
    for (int k = 0; k < KK; k++) {
        float xv = xs[k], hv = hs[k];
        const float* wx = rWx + (size_t)k * N4K + j;
        const float* wh = rWh + (size_t)k * N4K + j;
        ai += xv * wx[0]        + hv * wh[0];
        af += xv * wx[KK]       + hv * wh[KK];
        ag += xv * wx[2 * KK]   + hv * wh[2 * KK];
        ao += xv * wx[3 * KK]   + hv * wh[3 * KK];
    }
    float cn = sigf(af) * cr_in[b * KK + j] + sigf(ai) * tanhf(ag);
    float hn = sigf(ao) * tanhf(cn);
    cr_out[b * KK + j] = cn;
    hr_out[b * KK + j] = hn;
}

__global__ __launch_bounds__(256) void k_reader0(
    const float* __restrict__ x, const float* __restrict__ rWx,
    const float* __restrict__ rWh, const float* __restrict__ rb,
    const float* __restrict__ hr_in, const float* __restrict__ cr_in,
    float* __restrict__ hr_out, float* __restrict__ cr_out) {
    __shared__ float sh[2 * KK];
    reader_body(blockIdx.x, threadIdx.x, 0, x, rWx, rWh, rb, hr_in, cr_in, hr_out, cr_out, sh);
}

// ---------------- attention: (deferred mem update) + scores + online softmax ----------------
// grid (NC, B), 256 threads = 4 waves; wave handles 32 rows; lane holds K-slice [ln*4, ln*4+4)
__global__ __launch_bounds__(256) void k_attn(
    float* __restrict__ mem, const float* __restrict__ hr,
    float* __restrict__ s, float* __restrict__ partM, float* __restrict__ partS,
    float* __restrict__ partV, const float* __restrict__ hw_prev,
    const float* __restrict__ Mf, const float* __restrict__ Sf, int upd) {
    int c = blockIdx.x, b = blockIdx.y;
    int tid = threadIdx.x, w = tid >> 6, ln = tid & 63;

    float4 h4 = ((const float4*)(hr + b * KK))[ln];
    float4 w4 = make_float4(0.f, 0.f, 0.f, 0.f);
    float Mprev = 0.f, invS = 0.f;
    if (upd) {
        w4 = ((const float4*)(hw_prev + b * KK))[ln];
        Mprev = Mf[b];
        invS = 1.0f / Sf[b];
    }

    float Mw = -INFINITY, Sw = 0.f;
    float4 Vw = make_float4(0.f, 0.f, 0.f, 0.f);
    int l0 = c * RC + w * 32;
    for (int i = 0; i < 32; i++) {
        int l = l0 + i;
        float4* vp = (float4*)(mem + ((size_t)(b * LL + l)) * KK) + ln;
        float4 v = *vp;
        if (upd) {
            float z = expf(s[b * LL + l] - Mprev) * invS;
            float om = 1.0f - z;
            v.x = v.x * om + w4.x * z;
            v.y = v.y * om + w4.y * z;
            v.z = v.z * om + w4.z * z;
            v.w = v.w * om + w4.w * z;
            *vp = v;
        }
        float d = h4.x * v.x + h4.y * v.y + h4.z * v.z + h4.w * v.w;
#pragma unroll
        for (int m = 1; m < 64; m <<= 1) d += __shfl_xor(d, m, 64);
        if (ln == 0) s[b * LL + l] = d;
        // online softmax accumulate
        float nM = fmaxf(Mw, d);
        float sc = expf(Mw - nM);
        float e = expf(d - nM);
        Sw = Sw * sc + e;
        Vw.x = Vw.x * sc + e * v.x;
        Vw.y = Vw.y * sc + e * v.y;
        Vw.z = Vw.z * sc + e * v.z;
        Vw.w = Vw.w * sc + e * v.w;
        Mw = nM;
    }
    __shared__ float sM[4], sS[4];
    __shared__ float sV[4][KK];
    sV[w][ln * 4 + 0] = Vw.x;
    sV[w][ln * 4 + 1] = Vw.y;
    sV[w][ln * 4 + 2] = Vw.z;
    sV[w][ln * 4 + 3] = Vw.w;
    if (ln == 0) { sM[w] = Mw; sS[w] = Sw; }
    __syncthreads();
    int k = tid;
    float M = fmaxf(fmaxf(sM[0], sM[1]), fmaxf(sM[2], sM[3]));
    float e0 = expf(sM[0] - M), e1 = expf(sM[1] - M), e2 = expf(sM[2] - M), e3 = expf(sM[3] - M);
    float S = e0 * sS[0] + e1 * sS[1] + e2 * sS[2] + e3 * sS[3];
    float V = e0 * sV[0][k] + e1 * sV[1][k] + e2 * sV[2][k] + e3 * sV[3][k];
    partV[((size_t)(b * NC + c)) * KK + k] = V;
    if (tid == 0) {
        partM[b * NC + c] = M;
        partS[b * NC + c] = S;
    }
}

// ---------------- dense: reduce + composer + writer (blocks 0..31), reader(t+1) (blocks 32..63) --
__global__ __launch_bounds__(256) void k_dense(
    const float* __restrict__ partM, const float* __restrict__ partS,
    const float* __restrict__ partV, float* __restrict__ Mf, float* __restrict__ Sf,
    const float* __restrict__ hr_cur, const float* __restrict__ cW, const float* __restrict__ cb,
    const float* __restrict__ wWx, const float* __restrict__ wWh, const float* __restrict__ wb,
    const float* __restrict__ hw_in, const float* __restrict__ cw_in,
    float* __restrict__ hw_out, float* __restrict__ cw_out, float* __restrict__ out, int t,
    const float* __restrict__ x, const float* __restrict__ rWx, const float* __restrict__ rWh,
    const float* __restrict__ rb, const float* __restrict__ cr_in,
    float* __restrict__ hr_out, float* __restrict__ cr_out, int do_reader) {
    __shared__ float sh[1280];  // [0:256) hr, [256:512) m_rt, [512:1024) c_t, [1024:1280) hw_in
    int tid = threadIdx.x;
    if (blockIdx.x < Bb) {
        int b = blockIdx.x;
        float* sh_hr = sh;
        float* sh_m = sh + 256;
        float* sh_c = sh + 512;
        float* sh_hw = sh + 1024;
        // ---- softmax partial reduce -> m_rt, Mf, Sf
        float M = -INFINITY;
#pragma unroll
        for (int c = 0; c < NC; c++) M = fmaxf(M, partM[b * NC + c]);
        float S = 0.f, V = 0.f;
#pragma unroll
        for (int c = 0; c < NC; c++) {
            float e = expf(partM[b * NC + c] - M);
            S += e * partS[b * NC + c];
            V += e * partV[((size_t)(b * NC + c)) * KK + tid];
        }
        sh_m[tid] = V / S;
        sh_hr[tid] = hr_cur[b * KK + tid];
        sh_hw[tid] = hw_in[b * KK + tid];
        if (tid == 0) { Mf[b] = M; Sf[b] = S; }
        __syncthreads();
        // ---- composer: c_t = [hr, m_rt] @ cW + cb   (2 outputs per thread)
#pragma unroll
        for (int r = 0; r < 2; r++) {
            int n = tid + r * 256;
            float acc = cb[n];
#pragma unroll 4
            for (int k = 0; k < KK; k++)
                acc += sh_hr[k] * cW[(size_t)k * N2K + n] + sh_m[k] * cW[(size_t)(k + KK) * N2K + n];
            sh_c[n] = acc;
        }
        __syncthreads();
        // ---- writer LSTM
        int j = tid;
        float ai = wb[j], af = wb[j + KK], ag = wb[j + 2 * KK], ao = wb[j + 3 * KK];
#pragma unroll 4
        for (int k = 0; k < N2K; k++) {
            float cv = sh_c[k];
            const float* wx = wWx + (size_t)k * N4K + j;
            ai += cv * wx[0];
            af += cv * wx[KK];
            ag += cv * wx[2 * KK];
            ao += cv * wx[3 * KK];
        }
#pragma unroll 4
        for (int k = 0; k < KK; k++) {
            float hv = sh_hw[k];
            const float* wh = wWh + (size_t)k * N4K + j;
            ai += hv * wh[0];
            af += hv * wh[KK];
            ag += hv * wh[2 * KK];
            ao += hv * wh[3 * KK];
        }
        float cn = sigf(af) * cw_in[b * KK + j] + sigf(ai) * tanhf(ag);
        float hn = sigf(ao) * tanhf(cn);
        cw_out[b * KK + j] = cn;
        hw_out[b * KK + j] = hn;
        out[((size_t)b * LL + t) * KK + j] = hn;
    } else if (do_reader) {
        int b = blockIdx.x - Bb;
        reader_body(b, tid, t + 1, x, rWx, rWh, rb, hr_cur, cr_in, hr_out, cr_out, sh);
    }
}

// ---------------- host ----------------
extern "C" void kernel_launch(void* const* d_in, const int* in_sizes, int n_in,
                              void* d_out, int out_size, void* d_ws, size_t ws_size,
                              hipStream_t stream) {
    const float* x   = (const float*)d_in[0];
    const float* rWx = (const float*)d_in[1];
    const float* rWh = (const float*)d_in[2];
    const float* rb  = (const float*)d_in[3];
    const float* wWx = (const float*)d_in[4];
    const float* wWh = (const float*)d_in[5];
    const float* wb  = (const float*)d_in[6];
    const float* cW  = (const float*)d_in[7];
    const float* cb  = (const float*)d_in[8];
    float* out = (float*)d_out;

    float* ws = (float*)d_ws;
    const size_t MEM = (size_t)Bb * LL * KK;  // 8388608
    float* mem = ws;
    float* states = ws + MEM;                 // 8 state buffers, contiguous
    float* hr[2] = {states + 0 * Bb * KK, states + 1 * Bb * KK};
    float* cr[2] = {states + 2 * Bb * KK, states + 3 * Bb * KK};
    float* hw[2] = {states + 4 * Bb * KK, states + 5 * Bb * KK};
    float* cw[2] = {states + 6 * Bb * KK, states + 7 * Bb * KK};
    float* s     = states + 8 * Bb * KK;              // B*L
    float* partM = s + (size_t)Bb * LL;               // B*NC
    float* partS = partM + Bb * NC;                   // B*NC
    float* partV = partS + Bb * NC;                   // B*NC*K
    float* Mf    = partV + (size_t)Bb * NC * KK;      // B
    float* Sf    = Mf + Bb;                           // B

    k_init<<<4096, 256, 0, stream>>>(x, mem, states);
    k_reader0<<<Bb, 256, 0, stream>>>(x, rWx, rWh, rb, hr[0], cr[0], hr[1], cr[1]);

    for (int t = 0; t < LL; t++) {
        int pi = t & 1;        // state buffers holding step t-1 writer state / step t reader input parity
        int po = (t + 1) & 1;  // buffers written for step t
        k_attn<<<dim3(NC, Bb), 256, 0, stream>>>(mem, hr[po], s, partM, partS, partV,
                                                 hw[pi], Mf, Sf, t > 0 ? 1 : 0);
        k_dense<<<2 * Bb, 256, 0, stream>>>(partM, partS, partV, Mf, Sf, hr[po], cW, cb,
                                            wWx, wWh, wb, hw[pi], cw[pi], hw[po], cw[po], out, t,
                                            x, rWx, rWh, rb, cr[po], hr[pi], cr[pi],
                                            (t + 1 < LL) ? 1 : 0);
    }
}

// Round 2
// 104802.527 us; speedup vs baseline: 1.4568x; 1.4568x over previous
//
#include <hip/hip_runtime.h>
#include <math.h>

// NSE recurrent model, B=32, L=1024, K=256.
// Step t: reader LSTM -> hr_t ; scores s_l = hr_t . mem_l ; softmax z ;
// m_rt = sum z_l mem_l ; c_t = [hr,m_rt]@cW+cb ; writer LSTM -> hw_t ;
// mem = mem*(1-z) + hw_t*z  (update deferred into next step's score pass).
//
// 3 kernels/step: k_attn (2048 blk), k_mid (64 blk), k_wr (256 blk: writer+reader t+1).

#define Bb 32
#define LL 1024
#define KK 256
#define N4K 1024   // 4*K
#define N2K 512    // 2*K
#define NC 64      // L-chunks per batch row in attention kernel
#define RC 16      // rows per chunk = LL/NC

__device__ __forceinline__ float sigf(float v) { return 1.0f / (1.0f + __expf(-v)); }

// ---------------- init: mem <- x, zero LSTM states ----------------
__global__ void k_init(const float* __restrict__ x, float* __restrict__ mem,
                       float* __restrict__ states /* 8 * B*K floats */) {
    long long n = (long long)Bb * LL * KK;
    for (long long i = (long long)blockIdx.x * blockDim.x + threadIdx.x; i < n;
         i += (long long)gridDim.x * blockDim.x)
        mem[i] = x[i];
    for (int i = blockIdx.x * blockDim.x + threadIdx.x; i < 8 * Bb * KK;
         i += gridDim.x * blockDim.x)
        states[i] = 0.0f;
}

// ---------------- reader LSTM quarter-block body ----------------
// block covers 64 j-outputs (ch) x 4 gates; wave g handles gate g's 64 cols.
__device__ __forceinline__ void reader_quarter(
    int b, int ch, int tid, int t,
    const float* __restrict__ x, const float* __restrict__ rWx,
    const float* __restrict__ rWh, const float* __restrict__ rbv,
    const float* __restrict__ hr_in, const float* __restrict__ cr_in,
    float* __restrict__ hr_out, float* __restrict__ cr_out,
    float* sbuf /* >=512 */, float (*sg)[64]) {
    int g = tid >> 6, jj = tid & 63;
    sbuf[tid] = x[((size_t)b * LL + t) * KK + tid];
    sbuf[KK + tid] = hr_in[b * KK + tid];
    __syncthreads();
    int col = g * KK + ch * 64 + jj;
    float acc = rbv[col];
#pragma unroll 4
    for (int k = 0; k < KK; k++)
        acc += sbuf[k] * rWx[(size_t)k * N4K + col] + sbuf[KK + k] * rWh[(size_t)k * N4K + col];
    sg[g][jj] = acc;
    __syncthreads();
    if (tid < 64) {
        int j = ch * 64 + tid;
        float gi = sg[0][tid], gf = sg[1][tid], gg = sg[2][tid], go = sg[3][tid];
        float cn = sigf(gf) * cr_in[b * KK + j] + sigf(gi) * tanhf(gg);
        float hn = sigf(go) * tanhf(cn);
        cr_out[b * KK + j] = cn;
        hr_out[b * KK + j] = hn;
    }
}

__global__ __launch_bounds__(256) void k_rd(
    const float* __restrict__ x, const float* __restrict__ rWx,
    const float* __restrict__ rWh, const float* __restrict__ rbv,
    const float* __restrict__ hr_in, const float* __restrict__ cr_in,
    float* __restrict__ hr_out, float* __restrict__ cr_out, int t) {
    __shared__ float sbuf[2 * KK];
    __shared__ float sg[4][64];
    reader_quarter(blockIdx.x >> 2, blockIdx.x & 3, threadIdx.x, t, x, rWx, rWh, rbv,
                   hr_in, cr_in, hr_out, cr_out, sbuf, sg);
}

// ---------------- attention: (deferred mem update) + scores + online softmax ----------------
// grid (NC, B), 256 threads = 4 waves; wave handles 4 rows; lane holds K-slice [ln*4, ln*4+4)
__global__ __launch_bounds__(256) void k_attn(
    float* __restrict__ mem, const float* __restrict__ hr,
    float* __restrict__ s, float* __restrict__ partM, float* __restrict__ partS,
    float* __restrict__ partV, const float* __restrict__ hw_prev,
    const float* __restrict__ Mf, const float* __restrict__ Sf, int upd) {
    int c = blockIdx.x, b = blockIdx.y;
    int tid = threadIdx.x, w = tid >> 6, ln = tid & 63;

    float4 h4 = ((const float4*)(hr + b * KK))[ln];
    float4 w4 = make_float4(0.f, 0.f, 0.f, 0.f);
    float Mprev = 0.f, invS = 0.f;
    if (upd) {
        w4 = ((const float4*)(hw_prev + b * KK))[ln];
        Mprev = Mf[b];
        invS = 1.0f / Sf[b];
    }

    float Mw = -INFINITY, Sw = 0.f;
    float4 Vw = make_float4(0.f, 0.f, 0.f, 0.f);
    int l0 = c * RC + w * 4;
#pragma unroll
    for (int i = 0; i < 4; i++) {
        int l = l0 + i;
        float4* vp = (float4*)(mem + ((size_t)(b * LL + l)) * KK) + ln;
        float4 v = *vp;
        if (upd) {
            float z = __expf(s[b * LL + l] - Mprev) * invS;
            float om = 1.0f - z;
            v.x = v.x * om + w4.x * z;
            v.y = v.y * om + w4.y * z;
            v.z = v.z * om + w4.z * z;
            v.w = v.w * om + w4.w * z;
            *vp = v;
        }
        float d = h4.x * v.x + h4.y * v.y + h4.z * v.z + h4.w * v.w;
#pragma unroll
        for (int m = 1; m < 64; m <<= 1) d += __shfl_xor(d, m, 64);
        if (ln == 0) s[b * LL + l] = d;
        // online softmax accumulate
        float nM = fmaxf(Mw, d);
        float sc = __expf(Mw - nM);
        float e = __expf(d - nM);
        Sw = Sw * sc + e;
        Vw.x = Vw.x * sc + e * v.x;
        Vw.y = Vw.y * sc + e * v.y;
        Vw.z = Vw.z * sc + e * v.z;
        Vw.w = Vw.w * sc + e * v.w;
        Mw = nM;
    }
    __shared__ float sM4[4], sS4[4];
    __shared__ float sV[4][KK];
    sV[w][ln * 4 + 0] = Vw.x;
    sV[w][ln * 4 + 1] = Vw.y;
    sV[w][ln * 4 + 2] = Vw.z;
    sV[w][ln * 4 + 3] = Vw.w;
    if (ln == 0) { sM4[w] = Mw; sS4[w] = Sw; }
    __syncthreads();
    int k = tid;
    float M = fmaxf(fmaxf(sM4[0], sM4[1]), fmaxf(sM4[2], sM4[3]));
    float e0 = __expf(sM4[0] - M), e1 = __expf(sM4[1] - M);
    float e2 = __expf(sM4[2] - M), e3 = __expf(sM4[3] - M);
    float S = e0 * sS4[0] + e1 * sS4[1] + e2 * sS4[2] + e3 * sS4[3];
    float V = e0 * sV[0][k] + e1 * sV[1][k] + e2 * sV[2][k] + e3 * sV[3][k];
    partV[((size_t)(b * NC + c)) * KK + k] = V;
    if (tid == 0) {
        partM[b * NC + c] = M;
        partS[b * NC + c] = S;
    }
}

// ---------------- mid: softmax partial reduce + composer ----------------
// grid 64: b = bx>>1, col-chunk ch = bx&1 (256 cols each of the 512 composer outputs)
__global__ __launch_bounds__(256) void k_mid(
    const float* __restrict__ partM, const float* __restrict__ partS,
    const float* __restrict__ partV, float* __restrict__ Mf, float* __restrict__ Sf,
    const float* __restrict__ hr_cur, const float* __restrict__ cW,
    const float* __restrict__ cb, float* __restrict__ ct) {
    int b = blockIdx.x >> 1, ch = blockIdx.x & 1;
    int tid = threadIdx.x;
    __shared__ float sM[NC], sS[NC], sE[NC];
    __shared__ float sh_hr[KK], sh_m[KK];
    if (tid < NC) {
        sM[tid] = partM[b * NC + tid];
        sS[tid] = partS[b * NC + tid];
    }
    __syncthreads();
    float M = -INFINITY;
#pragma unroll
    for (int c2 = 0; c2 < NC; c2++) M = fmaxf(M, sM[c2]);
    if (tid < NC) sE[tid] = __expf(sM[tid] - M);
    __syncthreads();
    float S = 0.f;
#pragma unroll
    for (int c2 = 0; c2 < NC; c2++) S += sE[c2] * sS[c2];
    float V = 0.f;
    for (int c2 = 0; c2 < NC; c2++) V += sE[c2] * partV[((size_t)(b * NC + c2)) * KK + tid];
    sh_m[tid] = V / S;
    sh_hr[tid] = hr_cur[b * KK + tid];
    if (ch == 0 && tid == 0) { Mf[b] = M; Sf[b] = S; }
    __syncthreads();
    int col = ch * 256 + tid;
    float acc = cb[col];
#pragma unroll 4
    for (int k = 0; k < KK; k++)
        acc += sh_hr[k] * cW[(size_t)k * N2K + col] + sh_m[k] * cW[(size_t)(k + KK) * N2K + col];
    ct[b * N2K + col] = acc;
}

// ---------------- writer LSTM (blocks 0..127) + reader t+1 (blocks 128..255) --------
__global__ __launch_bounds__(256) void k_wr(
    const float* __restrict__ ct, const float* __restrict__ wWx,
    const float* __restrict__ wWh, const float* __restrict__ wb,
    const float* __restrict__ hw_in, const float* __restrict__ cw_in,
    float* __restrict__ hw_out, float* __restrict__ cw_out, float* __restrict__ out, int t,
    const float* __restrict__ x, const float* __restrict__ rWx,
    const float* __restrict__ rWh, const float* __restrict__ rbv,
    const float* __restrict__ hr_in, const float* __restrict__ cr_in,
    float* __restrict__ hr_out, float* __restrict__ cr_out, int do_reader) {
    __shared__ float sbuf[N2K + KK];
    __shared__ float sg[4][64];
    int tid = threadIdx.x;
    if (blockIdx.x < 128) {
        int b = blockIdx.x >> 2, ch = blockIdx.x & 3;
        int g = tid >> 6, jj = tid & 63;
        sbuf[tid] = ct[b * N2K + tid];
        sbuf[256 + tid] = ct[b * N2K + 256 + tid];
        sbuf[512 + tid] = hw_in[b * KK + tid];
        __syncthreads();
        int col = g * KK + ch * 64 + jj;
        float acc = wb[col];
#pragma unroll 4
        for (int k = 0; k < N2K; k++) acc += sbuf[k] * wWx[(size_t)k * N4K + col];
#pragma unroll 4
        for (int k = 0; k < KK; k++) acc += sbuf[N2K + k] * wWh[(size_t)k * N4K + col];
        sg[g][jj] = acc;
        __syncthreads();
        if (tid < 64) {
            int j = ch * 64 + tid;
            float gi = sg[0][tid], gf = sg[1][tid], gg = sg[2][tid], go = sg[3][tid];
            float cn = sigf(gf) * cw_in[b * KK + j] + sigf(gi) * tanhf(gg);
            float hn = sigf(go) * tanhf(cn);
            cw_out[b * KK + j] = cn;
            hw_out[b * KK + j] = hn;
            out[((size_t)b * LL + t) * KK + j] = hn;
        }
    } else if (do_reader) {
        int rbx = blockIdx.x - 128;
        reader_quarter(rbx >> 2, rbx & 3, tid, t + 1, x, rWx, rWh, rbv,
                       hr_in, cr_in, hr_out, cr_out, sbuf, sg);
    }
}

// ---------------- host ----------------
extern "C" void kernel_launch(void* const* d_in, const int* in_sizes, int n_in,
                              void* d_out, int out_size, void* d_ws, size_t ws_size,
                              hipStream_t stream) {
    const float* x   = (const float*)d_in[0];
    const float* rWx = (const float*)d_in[1];
    const float* rWh = (const float*)d_in[2];
    const float* rb  = (const float*)d_in[3];
    const float* wWx = (const float*)d_in[4];
    const float* wWh = (const float*)d_in[5];
    const float* wb  = (const float*)d_in[6];
    const float* cW  = (const float*)d_in[7];
    const float* cb  = (const float*)d_in[8];
    float* out = (float*)d_out;

    float* ws = (float*)d_ws;
    const size_t MEM = (size_t)Bb * LL * KK;  // 8388608
    float* mem = ws;
    float* states = ws + MEM;                 // 8 state buffers, contiguous
    float* hr[2] = {states + 0 * Bb * KK, states + 1 * Bb * KK};
    float* cr[2] = {states + 2 * Bb * KK, states + 3 * Bb * KK};
    float* hw[2] = {states + 4 * Bb * KK, states + 5 * Bb * KK};
    float* cw[2] = {states + 6 * Bb * KK, states + 7 * Bb * KK};
    float* s     = states + 8 * Bb * KK;              // B*L
    float* partM = s + (size_t)Bb * LL;               // B*NC
    float* partS = partM + Bb * NC;                   // B*NC
    float* partV = partS + Bb * NC;                   // B*NC*K
    float* Mf    = partV + (size_t)Bb * NC * KK;      // B
    float* Sf    = Mf + Bb;                           // B
    float* ct    = Sf + Bb;                           // B*2K

    k_init<<<4096, 256, 0, stream>>>(x, mem, states);
    k_rd<<<128, 256, 0, stream>>>(x, rWx, rWh, rb, hr[0], cr[0], hr[1], cr[1], 0);

    for (int t = 0; t < LL; t++) {
        int pi = t & 1;
        int po = (t + 1) & 1;
        k_attn<<<dim3(NC, Bb), 256, 0, stream>>>(mem, hr[po], s, partM, partS, partV,
                                                 hw[pi], Mf, Sf, t > 0 ? 1 : 0);
        k_mid<<<64, 256, 0, stream>>>(partM, partS, partV, Mf, Sf, hr[po], cW, cb, ct);
        k_wr<<<256, 256, 0, stream>>>(ct, wWx, wWh, wb, hw[pi], cw[pi], hw[po], cw[po], out, t,
                                      x, rWx, rWh, rb, hr[po], cr[po], hr[pi], cr[pi],
                                      (t + 1 < LL) ? 1 : 0);
    }
}

// Round 4
// 44916.208 us; speedup vs baseline: 3.3992x; 2.3333x over previous
//
#include <hip/hip_runtime.h>
#include <math.h>

// NSE recurrent model, B=32, L=1024, K=256.
// Step t: reader LSTM -> hr_t ; scores s_l = hr_t . mem_l ; softmax z ;
// m_rt = sum z_l mem_l ; c_t = [hr,m_rt]@cW+cb ; writer LSTM -> hw_t ;
// mem = mem*(1-z) + hw_t*z  (update deferred into next step's score pass).
//
// R4: R2 stream-ordered skeleton (proven correct) + k-split GEMV blocks:
//   k_attn (32x32=1024 blk), k_mid (256 blk), k_wr (1024 blk: 512 writer + 512 reader t+1).

#define Bb 32
#define LL 1024
#define KK 256
#define N4K 1024   // 4*K
#define N2K 512    // 2*K
#define NC 32      // L-chunks per batch row in attention kernel
#define RC 32      // rows per chunk = LL/NC

__device__ __forceinline__ float sigf(float v) { return 1.0f / (1.0f + __expf(-v)); }

// ---------------- init: mem <- x, zero LSTM states ----------------
__global__ void k_init(const float* __restrict__ x, float* __restrict__ mem,
                       float* __restrict__ states /* 8 * B*K floats */) {
    long long n = (long long)Bb * LL * KK;
    for (long long i = (long long)blockIdx.x * blockDim.x + threadIdx.x; i < n;
         i += (long long)gridDim.x * blockDim.x)
        mem[i] = x[i];
    for (int i = blockIdx.x * blockDim.x + threadIdx.x; i < 8 * Bb * KK;
         i += gridDim.x * blockDim.x)
        states[i] = 0.0f;
}

// ---------------- reader LSTM block: 16 j-outputs x 4 gates, 4-way k-split ----------
__device__ __forceinline__ void reader_blk(
    int b, int jg, int tid, int t1,
    const float* __restrict__ x, const float* __restrict__ rWx,
    const float* __restrict__ rWh, const float* __restrict__ rbv,
    const float* __restrict__ hr_in, const float* __restrict__ cr_in,
    float* __restrict__ hr_out, float* __restrict__ cr_out,
    float* shin /*512*/, float* sred /*256*/, float* sg /*64*/) {
    shin[tid] = x[((size_t)b * LL + t1) * KK + tid];
    shin[KK + tid] = hr_in[b * KK + tid];
    __syncthreads();
    int l = tid & 63, ks = tid >> 6;
    int g = l >> 4, jq = l & 15;
    int col = g * KK + jg * 16 + jq;
    float acc = (ks == 0) ? rbv[col] : 0.f;
    int k0 = ks * 128, k1 = k0 + 128;
    int kb = k1 < KK ? k1 : KK;
#pragma unroll 4
    for (int k = k0; k < kb; k++) acc += shin[k] * rWx[(size_t)k * N4K + col];
#pragma unroll 4
    for (int k = (k0 > KK ? k0 : KK); k < k1; k++)
        acc += shin[k] * rWh[(size_t)(k - KK) * N4K + col];
    sred[tid] = acc;
    __syncthreads();
    if (tid < 64) sg[tid] = sred[tid] + sred[tid + 64] + sred[tid + 128] + sred[tid + 192];
    __syncthreads();
    if (tid < 16) {
        int j = jg * 16 + tid;
        float gi = sg[tid], gf = sg[16 + tid], gG = sg[32 + tid], go = sg[48 + tid];
        float cn = sigf(gf) * cr_in[b * KK + j] + sigf(gi) * tanhf(gG);
        float hn = sigf(go) * tanhf(cn);
        cr_out[b * KK + j] = cn;
        hr_out[b * KK + j] = hn;
    }
}

__global__ __launch_bounds__(256) void k_rd(
    const float* __restrict__ x, const float* __restrict__ rWx,
    const float* __restrict__ rWh, const float* __restrict__ rbv,
    const float* __restrict__ hr_in, const float* __restrict__ cr_in,
    float* __restrict__ hr_out, float* __restrict__ cr_out, int t) {
    __shared__ float shin[N2K];
    __shared__ float sred[256];
    __shared__ float sg[64];
    reader_blk(blockIdx.x >> 4, blockIdx.x & 15, threadIdx.x, t, x, rWx, rWh, rbv,
               hr_in, cr_in, hr_out, cr_out, shin, sred, sg);
}

// ---------------- attention: (deferred mem update) + scores + online softmax ----------------
// grid (NC, B), 256 threads = 4 waves; wave handles 8 rows; lane holds K-slice [ln*4, ln*4+4)
__global__ __launch_bounds__(256) void k_attn(
    float* __restrict__ mem, const float* __restrict__ hr,
    float* __restrict__ s, float* __restrict__ partM, float* __restrict__ partS,
    float* __restrict__ partV, const float* __restrict__ hw_prev,
    const float* __restrict__ Mf, const float* __restrict__ Sf, int upd) {
    int c = blockIdx.x, b = blockIdx.y;
    int tid = threadIdx.x, w = tid >> 6, ln = tid & 63;

    float4 h4 = ((const float4*)(hr + b * KK))[ln];
    float4 w4 = make_float4(0.f, 0.f, 0.f, 0.f);
    float Mprev = 0.f, invS = 0.f;
    if (upd) {
        w4 = ((const float4*)(hw_prev + b * KK))[ln];
        Mprev = Mf[b];
        invS = 1.0f / Sf[b];
    }

    float Mw = -INFINITY, Sw = 0.f;
    float4 Vw = make_float4(0.f, 0.f, 0.f, 0.f);
    int l0 = c * RC + w * 8;
#pragma unroll
    for (int i = 0; i < 8; i++) {
        int l = l0 + i;
        float4* vp = (float4*)(mem + ((size_t)(b * LL + l)) * KK) + ln;
        float4 v = *vp;
        if (upd) {
            float z = __expf(s[b * LL + l] - Mprev) * invS;
            float om = 1.0f - z;
            v.x = v.x * om + w4.x * z;
            v.y = v.y * om + w4.y * z;
            v.z = v.z * om + w4.z * z;
            v.w = v.w * om + w4.w * z;
            *vp = v;
        }
        float d = h4.x * v.x + h4.y * v.y + h4.z * v.z + h4.w * v.w;
#pragma unroll
        for (int m = 1; m < 64; m <<= 1) d += __shfl_xor(d, m, 64);
        if (ln == 0) s[b * LL + l] = d;
        // online softmax accumulate
        float nM = fmaxf(Mw, d);
        float sc = __expf(Mw - nM);
        float e = __expf(d - nM);
        Sw = Sw * sc + e;
        Vw.x = Vw.x * sc + e * v.x;
        Vw.y = Vw.y * sc + e * v.y;
        Vw.z = Vw.z * sc + e * v.z;
        Vw.w = Vw.w * sc + e * v.w;
        Mw = nM;
    }
    __shared__ float sM4[4], sS4[4];
    __shared__ float sV[4][KK];
    sV[w][ln * 4 + 0] = Vw.x;
    sV[w][ln * 4 + 1] = Vw.y;
    sV[w][ln * 4 + 2] = Vw.z;
    sV[w][ln * 4 + 3] = Vw.w;
    if (ln == 0) { sM4[w] = Mw; sS4[w] = Sw; }
    __syncthreads();
    int k = tid;
    float M = fmaxf(fmaxf(sM4[0], sM4[1]), fmaxf(sM4[2], sM4[3]));
    float e0 = __expf(sM4[0] - M), e1 = __expf(sM4[1] - M);
    float e2 = __expf(sM4[2] - M), e3 = __expf(sM4[3] - M);
    float S = e0 * sS4[0] + e1 * sS4[1] + e2 * sS4[2] + e3 * sS4[3];
    float V = e0 * sV[0][k] + e1 * sV[1][k] + e2 * sV[2][k] + e3 * sV[3][k];
    partV[((size_t)(b * NC + c)) * KK + k] = V;
    if (tid == 0) {
        partM[b * NC + c] = M;
        partS[b * NC + c] = S;
    }
}

// ---------------- mid: softmax partial reduce + composer (4-way k-split, 64 cols/blk) ----
// grid 256: b = bx>>3, col-chunk cc = bx&7
__global__ __launch_bounds__(256) void k_mid(
    const float* __restrict__ partM, const float* __restrict__ partS,
    const float* __restrict__ partV, float* __restrict__ Mf, float* __restrict__ Sf,
    const float* __restrict__ hr_cur, const float* __restrict__ cW,
    const float* __restrict__ cb, float* __restrict__ ct) {
    int b = blockIdx.x >> 3, cc = blockIdx.x & 7;
    int tid = threadIdx.x;
    __shared__ float sMp[NC], sSp[NC], sEp[NC];
    __shared__ float shin[N2K];
    __shared__ float sred[256];
    if (tid < NC) {
        sMp[tid] = partM[b * NC + tid];
        sSp[tid] = partS[b * NC + tid];
    }
    __syncthreads();
    float M = -INFINITY;
#pragma unroll
    for (int c2 = 0; c2 < NC; c2++) M = fmaxf(M, sMp[c2]);
    if (tid < NC) sEp[tid] = __expf(sMp[tid] - M);
    __syncthreads();
    float S = 0.f;
#pragma unroll
    for (int c2 = 0; c2 < NC; c2++) S += sEp[c2] * sSp[c2];
    float V = 0.f;
    for (int c2 = 0; c2 < NC; c2++) V += sEp[c2] * partV[((size_t)(b * NC + c2)) * KK + tid];
    shin[tid] = hr_cur[b * KK + tid];
    shin[KK + tid] = V / S;
    if (cc == 0 && tid == 0) { Mf[b] = M; Sf[b] = S; }
    __syncthreads();
    int l = tid & 63, ks = tid >> 6;
    int col = cc * 64 + l;
    float acc = (ks == 0) ? cb[col] : 0.f;
    int k0 = ks * 128;
#pragma unroll 4
    for (int k = k0; k < k0 + 128; k++) acc += shin[k] * cW[(size_t)k * N2K + col];
    sred[tid] = acc;
    __syncthreads();
    if (tid < 64)
        ct[(size_t)b * N2K + cc * 64 + tid] =
            sred[tid] + sred[tid + 64] + sred[tid + 128] + sred[tid + 192];
}

// ---------------- writer LSTM (blocks 0..511, k-split) + reader t+1 (blocks 512..1023) ----
__global__ __launch_bounds__(256) void k_wr(
    const float* __restrict__ ct, const float* __restrict__ wWx,
    const float* __restrict__ wWh, const float* __restrict__ wb,
    const float* __restrict__ hw_in, const float* __restrict__ cw_in,
    float* __restrict__ hw_out, float* __restrict__ cw_out, float* __restrict__ out, int t,
    const float* __restrict__ x, const float* __restrict__ rWx,
    const float* __restrict__ rWh, const float* __restrict__ rbv,
    const float* __restrict__ hr_in, const float* __restrict__ cr_in,
    float* __restrict__ hr_out, float* __restrict__ cr_out, int do_reader) {
    __shared__ float shin[N2K];
    __shared__ float shw[KK];
    __shared__ float sred[256];
    __shared__ float sg[64];
    int tid = threadIdx.x;
    if (blockIdx.x < 512) {
        int b = blockIdx.x >> 4, jg = blockIdx.x & 15;
        shin[tid] = ct[(size_t)b * N2K + tid];
        shin[KK + tid] = ct[(size_t)b * N2K + KK + tid];
        shw[tid] = hw_in[b * KK + tid];
        __syncthreads();
        int l = tid & 63, ks = tid >> 6;
        int g = l >> 4, jq = l & 15;
        int col = g * KK + jg * 16 + jq;
        float acc = (ks == 0) ? wb[col] : 0.f;
        int k0 = ks * 192, k1 = k0 + 192;
        int kb = k1 < N2K ? k1 : N2K;
#pragma unroll 4
        for (int k = k0; k < kb; k++) acc += shin[k] * wWx[(size_t)k * N4K + col];
#pragma unroll 4
        for (int k = (k0 > N2K ? k0 : N2K); k < k1; k++)
            acc += shw[k - N2K] * wWh[(size_t)(k - N2K) * N4K + col];
        sred[tid] = acc;
        __syncthreads();
        if (tid < 64) sg[tid] = sred[tid] + sred[tid + 64] + sred[tid + 128] + sred[tid + 192];
        __syncthreads();
        if (tid < 16) {
            int j = jg * 16 + tid;
            float gi = sg[tid], gf = sg[16 + tid], gG = sg[32 + tid], go = sg[48 + tid];
            float cn = sigf(gf) * cw_in[b * KK + j] + sigf(gi) * tanhf(gG);
            float hn = sigf(go) * tanhf(cn);
            cw_out[b * KK + j] = cn;
            hw_out[b * KK + j] = hn;
            out[((size_t)b * LL + t) * KK + j] = hn;
        }
    } else if (do_reader) {
        int r2 = blockIdx.x - 512;
        reader_blk(r2 >> 4, r2 & 15, tid, t + 1, x, rWx, rWh, rbv,
                   hr_in, cr_in, hr_out, cr_out, shin, sred, sg);
    }
}

// ---------------- host ----------------
extern "C" void kernel_launch(void* const* d_in, const int* in_sizes, int n_in,
                              void* d_out, int out_size, void* d_ws, size_t ws_size,
                              hipStream_t stream) {
    const float* x   = (const float*)d_in[0];
    const float* rWx = (const float*)d_in[1];
    const float* rWh = (const float*)d_in[2];
    const float* rb  = (const float*)d_in[3];
    const float* wWx = (const float*)d_in[4];
    const float* wWh = (const float*)d_in[5];
    const float* wb  = (const float*)d_in[6];
    const float* cW  = (const float*)d_in[7];
    const float* cb  = (const float*)d_in[8];
    float* out = (float*)d_out;

    float* ws = (float*)d_ws;
    const size_t MEM = (size_t)Bb * LL * KK;  // 8388608
    float* mem = ws;
    float* states = ws + MEM;                 // 8 state buffers, contiguous
    float* hr[2] = {states + 0 * Bb * KK, states + 1 * Bb * KK};
    float* cr[2] = {states + 2 * Bb * KK, states + 3 * Bb * KK};
    float* hw[2] = {states + 4 * Bb * KK, states + 5 * Bb * KK};
    float* cw[2] = {states + 6 * Bb * KK, states + 7 * Bb * KK};
    float* s     = states + 8 * Bb * KK;              // B*L
    float* partM = s + (size_t)Bb * LL;               // B*NC
    float* partS = partM + Bb * NC;                   // B*NC
    float* partV = partS + Bb * NC;                   // B*NC*K
    float* Mf    = partV + (size_t)Bb * NC * KK;      // B
    float* Sf    = Mf + Bb;                           // B
    float* ct    = Sf + Bb;                           // B*2K

    k_init<<<4096, 256, 0, stream>>>(x, mem, states);
    k_rd<<<512, 256, 0, stream>>>(x, rWx, rWh, rb, hr[0], cr[0], hr[1], cr[1], 0);

    for (int t = 0; t < LL; t++) {
        int pi = t & 1;
        int po = (t + 1) & 1;
        k_attn<<<dim3(NC, Bb), 256, 0, stream>>>(mem, hr[po], s, partM, partS, partV,
                                                 hw[pi], Mf, Sf, t > 0 ? 1 : 0);
        k_mid<<<256, 256, 0, stream>>>(partM, partS, partV, Mf, Sf, hr[po], cW, cb, ct);
        k_wr<<<1024, 256, 0, stream>>>(ct, wWx, wWh, wb, hw[pi], cw[pi], hw[po], cw[po], out, t,
                                       x, rWx, rWh, rb, hr[po], cr[po], hr[pi], cr[pi],
                                       (t + 1 < LL) ? 1 : 0);
    }
}

// Round 5
// 34561.349 us; speedup vs baseline: 4.4176x; 1.2996x over previous
//
#include <hip/hip_runtime.h>
#include <math.h>

// NSE recurrent model, B=32, L=1024, K=256.
// Step t: reader LSTM -> hr_t ; scores s_l = hr_t . mem_l ; softmax z ;
// m_rt = sum z_l mem_l ; writer gates = [hr,m_rt]@Wf + hw@wWh + bf  (composer folded:
// Wf = cW@wWx, bf = cb@wWx + wb, precomputed once) ; mem update deferred to next step.
//
// R5: 2 kernels/step: k_attn (1024 blk), k_wrf (1024 blk: 512 fused writer + 512 reader t+1).

#define Bb 32
#define LL 1024
#define KK 256
#define N4K 1024   // 4*K
#define N2K 512    // 2*K
#define NC 32      // L-chunks per batch row in attention kernel
#define RC 32      // rows per chunk = LL/NC

__device__ __forceinline__ float sigf(float v) { return 1.0f / (1.0f + __expf(-v)); }

// ---------------- init: mem <- x, zero LSTM states ----------------
__global__ void k_init(const float* __restrict__ x, float* __restrict__ mem,
                       float* __restrict__ states /* 8 * B*K floats */) {
    long long n = (long long)Bb * LL * KK;
    for (long long i = (long long)blockIdx.x * blockDim.x + threadIdx.x; i < n;
         i += (long long)gridDim.x * blockDim.x)
        mem[i] = x[i];
    for (int i = blockIdx.x * blockDim.x + threadIdx.x; i < 8 * Bb * KK;
         i += gridDim.x * blockDim.x)
        states[i] = 0.0f;
}

// ---------------- pre: Wf = cW @ wWx (512x1024), bf = cb @ wWx + wb ----------------
// blocks 0..511: row kr of Wf; blocks 512..515: bf chunk
__global__ __launch_bounds__(256) void k_pre(
    const float* __restrict__ cW, const float* __restrict__ cb,
    const float* __restrict__ wWx, const float* __restrict__ wb,
    float* __restrict__ Wf, float* __restrict__ bf) {
    int tid = threadIdx.x;
    __shared__ float srow[N2K];
    if (blockIdx.x < N2K) {
        int kr = blockIdx.x;
        srow[tid] = cW[(size_t)kr * N2K + tid];
        srow[KK + tid] = cW[(size_t)kr * N2K + KK + tid];
        __syncthreads();
#pragma unroll
        for (int rep = 0; rep < 4; rep++) {
            int col = rep * 256 + tid;
            float a = 0.f;
#pragma unroll 4
            for (int c = 0; c < N2K; c++) a += srow[c] * wWx[(size_t)c * N4K + col];
            Wf[(size_t)kr * N4K + col] = a;
        }
    } else {
        int col = (blockIdx.x - N2K) * 256 + tid;
        float a = wb[col];
#pragma unroll 4
        for (int c = 0; c < N2K; c++) a += cb[c] * wWx[(size_t)c * N4K + col];
        bf[col] = a;
    }
}

// ---------------- reader LSTM block: 16 j-outputs x 4 gates, 4-way k-split ----------
__device__ __forceinline__ void reader_blk(
    int b, int jg, int tid, int t1,
    const float* __restrict__ x, const float* __restrict__ rWx,
    const float* __restrict__ rWh, const float* __restrict__ rbv,
    const float* __restrict__ hr_in, const float* __restrict__ cr_in,
    float* __restrict__ hr_out, float* __restrict__ cr_out,
    float* shin /*512*/, float* sred /*256*/, float* sg /*64*/) {
    shin[tid] = x[((size_t)b * LL + t1) * KK + tid];
    shin[KK + tid] = hr_in[b * KK + tid];
    __syncthreads();
    int l = tid & 63, ks = tid >> 6;
    int g = l >> 4, jq = l & 15;
    int col = g * KK + jg * 16 + jq;
    float acc = (ks == 0) ? rbv[col] : 0.f;
    int k0 = ks * 128, k1 = k0 + 128;
    int kb = k1 < KK ? k1 : KK;
#pragma unroll 4
    for (int k = k0; k < kb; k++) acc += shin[k] * rWx[(size_t)k * N4K + col];
#pragma unroll 4
    for (int k = (k0 > KK ? k0 : KK); k < k1; k++)
        acc += shin[k] * rWh[(size_t)(k - KK) * N4K + col];
    sred[tid] = acc;
    __syncthreads();
    if (tid < 64) sg[tid] = sred[tid] + sred[tid + 64] + sred[tid + 128] + sred[tid + 192];
    __syncthreads();
    if (tid < 16) {
        int j = jg * 16 + tid;
        float gi = sg[tid], gf = sg[16 + tid], gG = sg[32 + tid], go = sg[48 + tid];
        float cn = sigf(gf) * cr_in[b * KK + j] + sigf(gi) * tanhf(gG);
        float hn = sigf(go) * tanhf(cn);
        cr_out[b * KK + j] = cn;
        hr_out[b * KK + j] = hn;
    }
}

__global__ __launch_bounds__(256) void k_rd(
    const float* __restrict__ x, const float* __restrict__ rWx,
    const float* __restrict__ rWh, const float* __restrict__ rbv,
    const float* __restrict__ hr_in, const float* __restrict__ cr_in,
    float* __restrict__ hr_out, float* __restrict__ cr_out, int t) {
    __shared__ float shin[N2K];
    __shared__ float sred[256];
    __shared__ float sg[64];
    reader_blk(blockIdx.x >> 4, blockIdx.x & 15, threadIdx.x, t, x, rWx, rWh, rbv,
               hr_in, cr_in, hr_out, cr_out, shin, sred, sg);
}

// ---------------- attention: (deferred mem update) + scores + online softmax ----------------
// grid (NC, B), 256 threads = 4 waves; wave handles 8 rows; lane holds K-slice [ln*4, ln*4+4)
__global__ __launch_bounds__(256) void k_attn(
    float* __restrict__ mem, const float* __restrict__ hr,
    float* __restrict__ s, float* __restrict__ partM, float* __restrict__ partS,
    float* __restrict__ partV, const float* __restrict__ hw_prev,
    const float* __restrict__ Mf, const float* __restrict__ Sf, int upd) {
    int c = blockIdx.x, b = blockIdx.y;
    int tid = threadIdx.x, w = tid >> 6, ln = tid & 63;

    float4 h4 = ((const float4*)(hr + b * KK))[ln];
    float4 w4 = make_float4(0.f, 0.f, 0.f, 0.f);
    float Mprev = 0.f, invS = 0.f;
    if (upd) {
        w4 = ((const float4*)(hw_prev + b * KK))[ln];
        Mprev = Mf[b];
        invS = 1.0f / Sf[b];
    }

    float Mw = -INFINITY, Sw = 0.f;
    float4 Vw = make_float4(0.f, 0.f, 0.f, 0.f);
    int l0 = c * RC + w * 8;
#pragma unroll
    for (int i = 0; i < 8; i++) {
        int l = l0 + i;
        float4* vp = (float4*)(mem + ((size_t)(b * LL + l)) * KK) + ln;
        float4 v = *vp;
        if (upd) {
            float z = __expf(s[b * LL + l] - Mprev) * invS;
            float om = 1.0f - z;
            v.x = v.x * om + w4.x * z;
            v.y = v.y * om + w4.y * z;
            v.z = v.z * om + w4.z * z;
            v.w = v.w * om + w4.w * z;
            *vp = v;
        }
        float d = h4.x * v.x + h4.y * v.y + h4.z * v.z + h4.w * v.w;
#pragma unroll
        for (int m = 1; m < 64; m <<= 1) d += __shfl_xor(d, m, 64);
        if (ln == 0) s[b * LL + l] = d;
        // online softmax accumulate
        float nM = fmaxf(Mw, d);
        float sc = __expf(Mw - nM);
        float e = __expf(d - nM);
        Sw = Sw * sc + e;
        Vw.x = Vw.x * sc + e * v.x;
        Vw.y = Vw.y * sc + e * v.y;
        Vw.z = Vw.z * sc + e * v.z;
        Vw.w = Vw.w * sc + e * v.w;
        Mw = nM;
    }
    __shared__ float sM4[4], sS4[4];
    __shared__ float sV[4][KK];
    sV[w][ln * 4 + 0] = Vw.x;
    sV[w][ln * 4 + 1] = Vw.y;
    sV[w][ln * 4 + 2] = Vw.z;
    sV[w][ln * 4 + 3] = Vw.w;
    if (ln == 0) { sM4[w] = Mw; sS4[w] = Sw; }
    __syncthreads();
    int k = tid;
    float M = fmaxf(fmaxf(sM4[0], sM4[1]), fmaxf(sM4[2], sM4[3]));
    float e0 = __expf(sM4[0] - M), e1 = __expf(sM4[1] - M);
    float e2 = __expf(sM4[2] - M), e3 = __expf(sM4[3] - M);
    float S = e0 * sS4[0] + e1 * sS4[1] + e2 * sS4[2] + e3 * sS4[3];
    float V = e0 * sV[0][k] + e1 * sV[1][k] + e2 * sV[2][k] + e3 * sV[3][k];
    partV[((size_t)(b * NC + c)) * KK + k] = V;
    if (tid == 0) {
        partM[b * NC + c] = M;
        partS[b * NC + c] = S;
    }
}

// ---------------- fused writer (blocks 0..511) + reader t+1 (blocks 512..1023) -------
// writer block (b, jg): m_rt reduce from partials, then 64 gate-cols via 4-way k-split
// over 768 rows: [hr(256) | m_rt(256)] @ Wf  +  hw @ wWh, + bf.
__global__ __launch_bounds__(256) void k_wrf(
    const float* __restrict__ partM, const float* __restrict__ partS,
    const float* __restrict__ partV, const float* __restrict__ hr_cur,
    const float* __restrict__ Wf, const float* __restrict__ bf,
    const float* __restrict__ wWh,
    const float* __restrict__ hw_in, const float* __restrict__ cw_in,
    float* __restrict__ hw_out, float* __restrict__ cw_out,
    float* __restrict__ Mf, float* __restrict__ Sf, float* __restrict__ out, int t,
    const float* __restrict__ x, const float* __restrict__ rWx,
    const float* __restrict__ rWh, const float* __restrict__ rbv,
    const float* __restrict__ hr_in, const float* __restrict__ cr_in,
    float* __restrict__ hr_out, float* __restrict__ cr_out, int do_reader) {
    __shared__ float shin[N2K];
    __shared__ float shw[KK];
    __shared__ float sred[256];
    __shared__ float sg[64];
    __shared__ float sMp[NC], sSp[NC], sEp[NC];
    int tid = threadIdx.x;
    if (blockIdx.x < 512) {
        int b = blockIdx.x >> 4, jg = blockIdx.x & 15;
        if (tid < NC) {
            sMp[tid] = partM[b * NC + tid];
            sSp[tid] = partS[b * NC + tid];
        }
        __syncthreads();
        float M = -INFINITY;
#pragma unroll
        for (int c2 = 0; c2 < NC; c2++) M = fmaxf(M, sMp[c2]);
        if (tid < NC) sEp[tid] = __expf(sMp[tid] - M);
        __syncthreads();
        float S = 0.f;
#pragma unroll
        for (int c2 = 0; c2 < NC; c2++) S += sEp[c2] * sSp[c2];
        float V = 0.f;
        for (int c2 = 0; c2 < NC; c2++) V += sEp[c2] * partV[((size_t)(b * NC + c2)) * KK + tid];
        shin[tid] = hr_cur[b * KK + tid];
        shin[KK + tid] = V / S;
        shw[tid] = hw_in[b * KK + tid];
        if (jg == 0 && tid == 0) { Mf[b] = M; Sf[b] = S; }
        __syncthreads();
        int l = tid & 63, ks = tid >> 6;
        int g = l >> 4, jq = l & 15;
        int col = g * KK + jg * 16 + jq;
        float acc = (ks == 0) ? bf[col] : 0.f;
        int k0 = ks * 192, k1 = k0 + 192;
        int kb = k1 < N2K ? k1 : N2K;
#pragma unroll 4
        for (int k = k0; k < kb; k++) acc += shin[k] * Wf[(size_t)k * N4K + col];
#pragma unroll 4
        for (int k = (k0 > N2K ? k0 : N2K); k < k1; k++)
            acc += shw[k - N2K] * wWh[(size_t)(k - N2K) * N4K + col];
        sred[tid] = acc;
        __syncthreads();
        if (tid < 64) sg[tid] = sred[tid] + sred[tid + 64] + sred[tid + 128] + sred[tid + 192];
        __syncthreads();
        if (tid < 16) {
            int j = jg * 16 + tid;
            float gi = sg[tid], gf = sg[16 + tid], gG = sg[32 + tid], go = sg[48 + tid];
            float cn = sigf(gf) * cw_in[b * KK + j] + sigf(gi) * tanhf(gG);
            float hn = sigf(go) * tanhf(cn);
            cw_out[b * KK + j] = cn;
            hw_out[b * KK + j] = hn;
            out[((size_t)b * LL + t) * KK + j] = hn;
        }
    } else if (do_reader) {
        int r2 = blockIdx.x - 512;
        reader_blk(r2 >> 4, r2 & 15, tid, t + 1, x, rWx, rWh, rbv,
                   hr_in, cr_in, hr_out, cr_out, shin, sred, sg);
    }
}

// ---------------- host ----------------
extern "C" void kernel_launch(void* const* d_in, const int* in_sizes, int n_in,
                              void* d_out, int out_size, void* d_ws, size_t ws_size,
                              hipStream_t stream) {
    const float* x   = (const float*)d_in[0];
    const float* rWx = (const float*)d_in[1];
    const float* rWh = (const float*)d_in[2];
    const float* rb  = (const float*)d_in[3];
    const float* wWx = (const float*)d_in[4];
    const float* wWh = (const float*)d_in[5];
    const float* wb  = (const float*)d_in[6];
    const float* cW  = (const float*)d_in[7];
    const float* cb  = (const float*)d_in[8];
    float* out = (float*)d_out;

    float* ws = (float*)d_ws;
    const size_t MEM = (size_t)Bb * LL * KK;  // 8388608
    float* mem = ws;
    float* states = ws + MEM;                 // 8 state buffers, contiguous
    float* hr[2] = {states + 0 * Bb * KK, states + 1 * Bb * KK};
    float* cr[2] = {states + 2 * Bb * KK, states + 3 * Bb * KK};
    float* hw[2] = {states + 4 * Bb * KK, states + 5 * Bb * KK};
    float* cw[2] = {states + 6 * Bb * KK, states + 7 * Bb * KK};
    float* s     = states + 8 * Bb * KK;              // B*L
    float* partM = s + (size_t)Bb * LL;               // B*NC
    float* partS = partM + Bb * NC;                   // B*NC
    float* partV = partS + Bb * NC;                   // B*NC*K
    float* Mf    = partV + (size_t)Bb * NC * KK;      // B
    float* Sf    = Mf + Bb;                           // B
    float* Wf    = Sf + Bb;                           // 512*1024
    float* bf    = Wf + (size_t)N2K * N4K;            // 1024

    k_init<<<4096, 256, 0, stream>>>(x, mem, states);
    k_pre<<<516, 256, 0, stream>>>(cW, cb, wWx, wb, Wf, bf);
    k_rd<<<512, 256, 0, stream>>>(x, rWx, rWh, rb, hr[0], cr[0], hr[1], cr[1], 0);

    for (int t = 0; t < LL; t++) {
        int pi = t & 1;
        int po = (t + 1) & 1;
        k_attn<<<dim3(NC, Bb), 256, 0, stream>>>(mem, hr[po], s, partM, partS, partV,
                                                 hw[pi], Mf, Sf, t > 0 ? 1 : 0);
        k_wrf<<<1024, 256, 0, stream>>>(partM, partS, partV, hr[po], Wf, bf, wWh,
                                        hw[pi], cw[pi], hw[po], cw[po], Mf, Sf, out, t,
                                        x, rWx, rWh, rb, hr[po], cr[po], hr[pi], cr[pi],
                                        (t + 1 < LL) ? 1 : 0);
    }
}